// Round 2
// baseline (1615.440 us; speedup 1.0000x reference)
//
#include <hip/hip_runtime.h>

// UpSampling: out[row][0:N] = 0, out[row][N+e] = 0.5*(data[row][e0] + data[row][e1])
// rows = B*C = 512, N = 100000, E = 200000, all f32.
//
// Round-2 structure: the bottleneck was 204.8M divergent 4B gathers (transaction-
// rate bound: 906 GB/s, VALU 2.8%, nothing saturated). Fix: SpMM-style transpose.
//   Kernel A: transpose data [512][N] -> dt [N][512] in workspace (+ zero head).
//   Kernel B: per 64-edge block, gather dt[v][r0:r0+64] as coalesced 256B reads,
//             LDS-tile transpose (rows x edges), write out coalesced 64B lines.
// Every memory op is now line-granular; ~64x fewer memory transactions.

constexpr int B_ = 4, C_ = 128, N_ = 100000, E_ = 200000;
constexpr int ROWS = B_ * C_;            // 512
constexpr long long W = N_ + E_;         // 300000 floats per output row
constexpr int R = ROWS;

// ---- kernel A geometry: transpose tiles of 32 vertices x 64 rows ----
constexpr int NT = N_ / 32;              // 3125 vertex-tiles (exact)
constexpr int RT = R / 64;               // 8 row-tiles (exact)
constexpr int TB = NT * RT;              // 25000 transpose blocks
constexpr int NQ = N_ / 4;               // 25000 float4 zeros per row
constexpr int ZBLK = (R * NQ) / (256 * 4); // 12500 zero blocks (4 float4/thread, exact)

// ---- kernel B geometry: 64 edges per block, 8 chunks of 64 rows ----
constexpr int MBLK = E_ / 64;            // 3125 mid blocks (exact)

// ---- fallback geometry (round-1 kernel) ----
constexpr int FMT = E_ / 8;              // 25000 mid threads per row
constexpr int FZT = NQ / 2;              // 12500 zero threads per row
constexpr int FMB = (FMT + 255) / 256;   // 98
constexpr int FZB = (FZT + 255) / 256;   // 49
constexpr int FP  = FMB + FZB;           // 147

typedef float  vf4 __attribute__((ext_vector_type(4)));
typedef int    vi4 __attribute__((ext_vector_type(4)));

// ================= kernel A: transpose + zero head =================
__global__ __launch_bounds__(256) void prep_kernel(
    const float* __restrict__ data,
    float*       __restrict__ dt,
    float*       __restrict__ out)
{
    const int t = threadIdx.x;
    if (blockIdx.x < TB) {
        const int bt = blockIdx.x;
        const int nt = bt % NT, rt = bt / NT;
        const int n0 = nt * 32, r0 = rt * 64;
        __shared__ float lds[32][65];
        const int rl = t >> 5, n = t & 31;
        #pragma unroll
        for (int it = 0; it < 8; ++it) {
            const int r = rl + it * 8;
            lds[n][r] = data[(size_t)(r0 + r) * N_ + n0 + n];
        }
        __syncthreads();
        const int v = t >> 3, rs = (t & 7) << 3;
        const float* lp = &lds[v][rs];
        vf4 a = { lp[0], lp[1], lp[2], lp[3] };
        vf4 b = { lp[4], lp[5], lp[6], lp[7] };
        vf4* p = (vf4*)(dt + (size_t)(n0 + v) * R + r0 + rs);
        p[0] = a;                    // dt is re-read by kernel B: keep cacheable
        p[1] = b;
    } else {
        // zero head: flat float4 index over 512 rows x 25000 f4/row
        const int flat = (blockIdx.x - TB) * 1024 + t * 4;   // multiple of 4
        const int row = flat / 25000;
        const int col = flat - row * 25000;                  // multiple of 4
        vf4* zp = (vf4*)(out + (size_t)row * (size_t)W) + col;
        vf4 z = (vf4)(0.f);
        __builtin_nontemporal_store(z, zp + 0);
        __builtin_nontemporal_store(z, zp + 1);
        __builtin_nontemporal_store(z, zp + 2);
        __builtin_nontemporal_store(z, zp + 3);
    }
}

// ================= kernel B: mids via coalesced dt reads =================
__global__ __launch_bounds__(256) void mids_kernel(
    const float* __restrict__ dt,
    const int2*  __restrict__ ed,
    float*       __restrict__ out)
{
    __shared__ float lds[64][65];
    const int t  = threadIdx.x;
    const int wv = t >> 6;          // wave 0..3: 16 edges each
    const int ln = t & 63;          // lane = row within chunk
    const int e_base = blockIdx.x * 64;

    // hoist this wave's 16 edges into registers (wave-uniform values)
    int v0[16], v1[16];
    #pragma unroll
    for (int j = 0; j < 16; ++j) {
        int2 e = ed[e_base + wv * 16 + j];
        v0[j] = e.x; v1[j] = e.y;
    }

    for (int r0 = 0; r0 < R; r0 += 64) {
        const float* dp = dt + r0 + ln;
        float mv[16];
        #pragma unroll
        for (int j = 0; j < 16; ++j) {
            // two coalesced 256B wave-reads per edge
            mv[j] = 0.5f * (dp[(size_t)v0[j] * R] + dp[(size_t)v1[j] * R]);
        }
        #pragma unroll
        for (int j = 0; j < 16; ++j)
            lds[ln][wv * 16 + j] = mv[j];
        __syncthreads();

        // write: 64 rows x 64 edges; each thread = one 64B line of one row
        const int r = t >> 2, seg = (t & 3) << 4;
        const float* lp = &lds[r][seg];
        vf4 m0 = { lp[ 0], lp[ 1], lp[ 2], lp[ 3] };
        vf4 m1 = { lp[ 4], lp[ 5], lp[ 6], lp[ 7] };
        vf4 m2 = { lp[ 8], lp[ 9], lp[10], lp[11] };
        vf4 m3 = { lp[12], lp[13], lp[14], lp[15] };
        vf4* op = (vf4*)(out + (size_t)(r0 + r) * (size_t)W + N_ + e_base + seg);
        __builtin_nontemporal_store(m0, op + 0);
        __builtin_nontemporal_store(m1, op + 1);
        __builtin_nontemporal_store(m2, op + 2);
        __builtin_nontemporal_store(m3, op + 3);
        __syncthreads();   // protect lds before next chunk overwrites
    }
}

// ================= fallback: round-1 kernel (if ws too small) =================
__global__ __launch_bounds__(256) void upsample_fallback(
    const float* __restrict__ data,
    const vi4*   __restrict__ e4,
    float*       __restrict__ out)
{
    const int flat = blockIdx.x;
    const int xcd  = flat & 7;
    const int j    = flat >> 3;
    const int rg   = j / FP;
    const int bx   = j - rg * FP;
    const int row  = xcd * (ROWS / 8) + rg;

    float* __restrict__ orow = out + (size_t)row * (size_t)W;
    const int tid = threadIdx.x;

    if (bx < FMB) {
        const int t = bx * 256 + tid;
        if (t < FMT) {
            const float* __restrict__ drow = data + (size_t)row * (size_t)N_;
            vi4 a = e4[4 * t + 0];
            vi4 b = e4[4 * t + 1];
            vi4 c = e4[4 * t + 2];
            vi4 d = e4[4 * t + 3];
            vf4 m0, m1;
            m0.x = 0.5f * (drow[a.x] + drow[a.y]);
            m0.y = 0.5f * (drow[a.z] + drow[a.w]);
            m0.z = 0.5f * (drow[b.x] + drow[b.y]);
            m0.w = 0.5f * (drow[b.z] + drow[b.w]);
            m1.x = 0.5f * (drow[c.x] + drow[c.y]);
            m1.y = 0.5f * (drow[c.z] + drow[c.w]);
            m1.z = 0.5f * (drow[d.x] + drow[d.y]);
            m1.w = 0.5f * (drow[d.z] + drow[d.w]);
            vf4* mq = (vf4*)(orow + N_);
            __builtin_nontemporal_store(m0, mq + 2 * t);
            __builtin_nontemporal_store(m1, mq + 2 * t + 1);
        }
    } else {
        const int t = (bx - FMB) * 256 + tid;
        if (t < FZT) {
            vf4 z = (vf4)(0.f);
            vf4* zq = (vf4*)orow;
            __builtin_nontemporal_store(z, zq + 2 * t);
            __builtin_nontemporal_store(z, zq + 2 * t + 1);
        }
    }
}

extern "C" void kernel_launch(void* const* d_in, const int* in_sizes, int n_in,
                              void* d_out, int out_size, void* d_ws, size_t ws_size,
                              hipStream_t stream) {
    const float* data = (const float*)d_in[0];
    float*       out  = (float*)d_out;
    const size_t DT_BYTES = (size_t)N_ * (size_t)R * sizeof(float);  // 204.8 MB

    if (d_ws != nullptr && ws_size >= DT_BYTES) {
        float* dt = (float*)d_ws;
        prep_kernel<<<dim3(TB + ZBLK), 256, 0, stream>>>(data, dt, out);
        mids_kernel<<<dim3(MBLK), 256, 0, stream>>>(dt, (const int2*)d_in[1], out);
    } else {
        upsample_fallback<<<dim3(FP * ROWS), 256, 0, stream>>>(
            data, (const vi4*)d_in[1], out);
    }
}

// Round 3
// 874.503 us; speedup vs baseline: 1.8473x; 1.8473x over previous
//
#include <hip/hip_runtime.h>

// UpSampling: out[row][0:N] = 0, out[row][N+e] = 0.5*(data[row][e0] + data[row][e1])
// rows = B*C = 512, N = 100000, E = 200000, all f32.
//
// Round-3 structure (SpMM transpose, v2):
//   Kernel P: transpose data [512][N] -> dt [N][512] (workspace) + zero head.
//             All stores instruction-coalesced (consecutive lanes -> consecutive 16B).
//   Kernel M: one WAVE owns 32 edges; loops 8 chunks of 64 rows.
//             Reads dt[v][r0:r0+64] = coalesced 256B; LDS [64][33] per-wave tile
//             (no __syncthreads anywhere); writes full aligned 128B lines
//             (8 lanes x 16B per row). Fixes round-2's 2.5x write amplification
//             (partial-line NT stores) and barrier-coupled latency exposure.

constexpr int B_ = 4, C_ = 128, N_ = 100000, E_ = 200000;
constexpr int ROWS = B_ * C_;            // 512
constexpr int R = ROWS;
constexpr long long W = N_ + E_;         // 300000 floats per output row

// ---- kernel P geometry ----
constexpr int NT = N_ / 32;              // 3125 vertex-tiles
constexpr int RT = R / 64;               // 8 row-tiles
constexpr int TB = NT * RT;              // 25000 transpose blocks
constexpr int ZVF4 = (R * (N_ / 4));     // 12.8M float4 zeros total
constexpr int ZBLK = ZVF4 / (256 * 8);   // 6250 zero blocks (8 vf4/thread, exact)

// ---- kernel M geometry: 32 edges per wave, 2 waves per block ----
constexpr int MBLK = E_ / 64;            // 3125 blocks (exact)

// ---- fallback geometry (round-1 kernel) ----
constexpr int FMT = E_ / 8;
constexpr int FZT = (N_ / 4) / 2;
constexpr int FMB = (FMT + 255) / 256;   // 98
constexpr int FZB = (FZT + 255) / 256;   // 49
constexpr int FP  = FMB + FZB;           // 147

typedef float  vf4 __attribute__((ext_vector_type(4)));
typedef int    vi4 __attribute__((ext_vector_type(4)));

// ================= kernel P: transpose + zero head =================
__global__ __launch_bounds__(256) void prep_kernel(
    const float* __restrict__ data,
    float*       __restrict__ dt,
    float*       __restrict__ out)
{
    const int t = threadIdx.x;
    if (blockIdx.x < TB) {
        const int bt = blockIdx.x;
        const int nt = bt % NT, rt = bt / NT;
        const int n0 = nt * 32, r0 = rt * 64;
        __shared__ float lds[32][65];
        // read: 32 vertices x 64 rows; lanes n=0..31 contiguous -> 128B/row (line-aligned)
        const int n = t & 31, rb = t >> 5;       // rb 0..7
        #pragma unroll
        for (int it = 0; it < 8; ++it) {
            const int r = rb + it * 8;
            lds[n][r] = data[(size_t)(r0 + r) * N_ + n0 + n];
        }
        __syncthreads();
        // write: 16 lanes per vertex, each 16B -> 256B contiguous per vertex
        const int v = t >> 4, rs = (t & 15) * 4;
        #pragma unroll
        for (int ps = 0; ps < 2; ++ps) {
            const int vv = v + 16 * ps;
            vf4 a = { lds[vv][rs], lds[vv][rs + 1], lds[vv][rs + 2], lds[vv][rs + 3] };
            *(vf4*)(dt + (size_t)(n0 + vv) * R + r0 + rs) = a;   // cacheable: re-read by M
        }
    } else {
        // zero head: lane-interleaved -> each instruction = 1KB contiguous per wave
        const int base = (blockIdx.x - TB) * 2048;
        vf4 z = (vf4)(0.f);
        #pragma unroll
        for (int i = 0; i < 8; ++i) {
            const int f = base + i * 256 + t;          // flat vf4 index
            const int row = f / 25000;
            const int col = f - row * 25000;
            __builtin_nontemporal_store(z, (vf4*)(out + (size_t)row * (size_t)W) + col);
        }
    }
}

// ================= kernel M: mids, wave-private, no barriers =================
__global__ __launch_bounds__(128) void mids_kernel(
    const float* __restrict__ dt,
    const int2*  __restrict__ ed,
    float*       __restrict__ out)
{
    __shared__ float lds[2][64][33];                 // per-wave padded tile
    const int t   = threadIdx.x;
    const int wid = t >> 6, ln = t & 63;
    const int we  = (blockIdx.x * 2 + wid) * 32;     // this wave's 32 edges

    // wave-uniform edge offsets -> scalar regs
    int s0[32], s1[32];
    #pragma unroll
    for (int j = 0; j < 32; ++j) {
        int2 e = ed[we + j];
        s0[j] = __builtin_amdgcn_readfirstlane(e.x) * R;
        s1[j] = __builtin_amdgcn_readfirstlane(e.y) * R;
    }

    const float* __restrict__ dtl = dt + ln;

    for (int r0 = 0; r0 < R; r0 += 64) {
        // 64 coalesced 256B gathers (lane = row)
        float mv[32];
        #pragma unroll
        for (int j = 0; j < 32; ++j)
            mv[j] = 0.5f * (dtl[s0[j] + r0] + dtl[s1[j] + r0]);

        // LDS transpose tile: write bank = (ln + j) % 32, conflict-free
        #pragma unroll
        for (int j = 0; j < 32; ++j)
            lds[wid][ln][j] = mv[j];
        asm volatile("s_waitcnt lgkmcnt(0)" ::: "memory");

        // out: 8 lanes/row x 16B = one full aligned 128B line per row,
        // 8 rows per instruction, 8 passes -> 64 rows
        #pragma unroll
        for (int p = 0; p < 8; ++p) {
            const int r = p * 8 + (ln >> 3);
            const int c = (ln & 7) * 4;
            vf4 m = { lds[wid][r][c],     lds[wid][r][c + 1],
                      lds[wid][r][c + 2], lds[wid][r][c + 3] };
            __builtin_nontemporal_store(
                m, (vf4*)(out + (size_t)(r0 + r) * (size_t)W + N_ + we + c));
        }
        asm volatile("s_waitcnt lgkmcnt(0)" ::: "memory");  // WAR guard before next chunk
    }
}

// ================= fallback (ws too small): round-1 kernel =================
__global__ __launch_bounds__(256) void upsample_fallback(
    const float* __restrict__ data,
    const vi4*   __restrict__ e4,
    float*       __restrict__ out)
{
    const int flat = blockIdx.x;
    const int xcd  = flat & 7;
    const int j    = flat >> 3;
    const int rg   = j / FP;
    const int bx   = j - rg * FP;
    const int row  = xcd * (ROWS / 8) + rg;

    float* __restrict__ orow = out + (size_t)row * (size_t)W;
    const int tid = threadIdx.x;

    if (bx < FMB) {
        const int t = bx * 256 + tid;
        if (t < FMT) {
            const float* __restrict__ drow = data + (size_t)row * (size_t)N_;
            vi4 a = e4[4 * t + 0];
            vi4 b = e4[4 * t + 1];
            vi4 c = e4[4 * t + 2];
            vi4 d = e4[4 * t + 3];
            vf4 m0, m1;
            m0.x = 0.5f * (drow[a.x] + drow[a.y]);
            m0.y = 0.5f * (drow[a.z] + drow[a.w]);
            m0.z = 0.5f * (drow[b.x] + drow[b.y]);
            m0.w = 0.5f * (drow[b.z] + drow[b.w]);
            m1.x = 0.5f * (drow[c.x] + drow[c.y]);
            m1.y = 0.5f * (drow[c.z] + drow[c.w]);
            m1.z = 0.5f * (drow[d.x] + drow[d.y]);
            m1.w = 0.5f * (drow[d.z] + drow[d.w]);
            vf4* mq = (vf4*)(orow + N_);
            __builtin_nontemporal_store(m0, mq + 2 * t);
            __builtin_nontemporal_store(m1, mq + 2 * t + 1);
        }
    } else {
        const int t = (bx - FMB) * 256 + tid;
        if (t < FZT) {
            vf4 z = (vf4)(0.f);
            vf4* zq = (vf4*)orow;
            __builtin_nontemporal_store(z, zq + 2 * t);
            __builtin_nontemporal_store(z, zq + 2 * t + 1);
        }
    }
}

extern "C" void kernel_launch(void* const* d_in, const int* in_sizes, int n_in,
                              void* d_out, int out_size, void* d_ws, size_t ws_size,
                              hipStream_t stream) {
    const float* data = (const float*)d_in[0];
    float*       out  = (float*)d_out;
    const size_t DT_BYTES = (size_t)N_ * (size_t)R * sizeof(float);  // 204.8 MB

    if (d_ws != nullptr && ws_size >= DT_BYTES) {
        float* dt = (float*)d_ws;
        prep_kernel<<<dim3(TB + ZBLK), 256, 0, stream>>>(data, dt, out);
        mids_kernel<<<dim3(MBLK), 128, 0, stream>>>(dt, (const int2*)d_in[1], out);
    } else {
        upsample_fallback<<<dim3(FP * ROWS), 256, 0, stream>>>(
            data, (const vi4*)d_in[1], out);
    }
}